// Round 6
// baseline (192.870 us; speedup 1.0000x reference)
//
#include <hip/hip_runtime.h>
#include <hip/hip_bf16.h>

typedef __hip_bfloat16 bf16;
typedef __attribute__((ext_vector_type(8))) short s16x8;
typedef __attribute__((ext_vector_type(4))) float f32x4;

#define SWZ(c) ((((c) ^ ((c) >> 3)) & 7) << 4)   // 128B-row swizzle, XOR bits 4-6

__device__ __forceinline__ unsigned short f2b(float x){
    __hip_bfloat16 h = __float2bfloat16(x);
    return __builtin_bit_cast(unsigned short, h);
}
__device__ __forceinline__ float b2f(unsigned short s){
    unsigned int u = (unsigned int)s << 16;
    return __builtin_bit_cast(float, u);
}

// ---------------- K0: per-h tables via direct complex exp ------------------
// Qh[h][n2=128][t=64]     : Q[2n][t]=Re r^{63-t}, Q[2n+1][t]=Im r^{63-t} (bf16)
// Pmh/Pml[h][j=64][n2=128]: Pm[j][2n]=Re(2Ck r^{j+1}), [2n+1]=-Im(...)   (hi+lo)
// Klh/Kll[h][j=64][t=64]  : Kd[j-t] (t<=j) + D*delta(t==j)  [row j!]     (hi+lo)
// rLtab[h][n][2]=r^64 ; rL2tab[h][n][2]=r^4096  (f32, scan)
__global__ __launch_bounds__(256) void k0_setup(const float* __restrict__ log_dt,
        const float* __restrict__ C_ri, const float* __restrict__ log_A_real,
        const float* __restrict__ A_imag, const float* __restrict__ Dp,
        float* __restrict__ rLtab, float* __restrict__ rL2tab,
        short* __restrict__ Qh,
        short* __restrict__ Pmh, short* __restrict__ Pml,
        short* __restrict__ Klh, short* __restrict__ Kll)
{
    __shared__ float arr[64][65];   // Pm_re staging: arr[j][n] = Re(2Ck r^{j+1})
    __shared__ float a0[64];        // 2*Re(Ck)
    __shared__ float kd[64];
    int h = blockIdx.x;
    int tid = threadIdx.x;
    int n = tid & 63, g = tid >> 6;
    int hn = h * 64 + n;
    double dtd  = exp((double)log_dt[h]);
    float  Aref = -expf(log_A_real[hn]);
    double Ared = (double)Aref;
    double Aimd = (double)A_imag[hn];
    double adt  = Aimd * dtd;                 // angle per unit exponent
    float  mdt  = (float)(Ared * dtd);        // log-magnitude per unit exponent
    // cexp(e) = r^e
    auto cexp = [&](float e, float& re, float& im){
        double a = adt * (double)e;
        double k = floor(a * 0.15915494309189535);
        float ang = (float)(a - k * 6.283185307179586);
        float si, co;
        __sincosf(ang, &si, &co);
        float mag = expf(mdt * e);
        re = mag * co; im = mag * si;
    };
    // Ck = C * (r-1)/A
    float rre, rim; cexp(1.f, rre, rim);
    float Cre = C_ri[2 * hn], Cim = C_ri[2 * hn + 1];
    float emre = rre - 1.f, emim = rim;
    float inva2 = 1.f / (Aref * Aref + (float)(Aimd * Aimd));
    float qre_ = (emre * Aref + emim * (float)Aimd) * inva2;
    float qim_ = (emim * Aref - emre * (float)Aimd) * inva2;
    float ckre = Cre * qre_ - Cim * qim_;
    float ckim = Cre * qim_ + Cim * qre_;
    // Q rows 2n,2n+1 for t in [16g,16g+16)
    {
        short* q0 = Qh + (size_t)h * 8192 + (2 * n) * 64;
        short* q1 = q0 + 64;
        for (int t = 16 * g; t < 16 * g + 16; ++t) {
            float pre, pim; cexp((float)(63 - t), pre, pim);
            q0[t] = (short)f2b(pre);
            q1[t] = (short)f2b(pim);
        }
    }
    if (g == 0) {   // r^64
        float pre, pim; cexp(64.f, pre, pim);
        rLtab[2 * hn] = pre; rLtab[2 * hn + 1] = pim;
    }
    if (g == 1) {   // r^4096
        float pre, pim; cexp(4096.f, pre, pim);
        rL2tab[2 * hn] = pre; rL2tab[2 * hn + 1] = pim;
    }
    if (g == 2) a0[n] = 2.f * ckre;
    // Pm rows j in [16g,16g+16)
    {
        short* pmh = Pmh + (size_t)h * 8192;
        short* pml = Pml + (size_t)h * 8192;
        for (int j = 16 * g; j < 16 * g + 16; ++j) {
            float pre, pim; cexp((float)(j + 1), pre, pim);
            float wre = 2.f * (ckre * pre - ckim * pim);
            float wim = 2.f * (ckre * pim + ckim * pre);
            unsigned short h0 = f2b(wre), h1 = f2b(-wim);
            pmh[j * 128 + 2 * n]     = (short)h0;
            pml[j * 128 + 2 * n]     = (short)f2b(wre - b2f(h0));
            pmh[j * 128 + 2 * n + 1] = (short)h1;
            pml[j * 128 + 2 * n + 1] = (short)f2b(-wim - b2f(h1));
            arr[j][n] = wre;
        }
    }
    __syncthreads();
    if (tid < 64) {                 // Kd[d]
        int d = tid;
        float s = 0.f;
        if (d == 0) { for (int k = 0; k < 64; ++k) s += a0[k]; }
        else        { for (int k = 0; k < 64; ++k) s += arr[d - 1][k]; }
        kd[d] = s;
    }
    __syncthreads();
    // Klow ROW j=n (storage [j][t], same as R4-proven layout), D on diagonal
    {
        float Dh = Dp[h];
        short* klh = Klh + (size_t)h * 4096 + n * 64;   // row j=n
        short* kll = Kll + (size_t)h * 4096 + n * 64;
        for (int t = 16 * g; t < 16 * g + 16; ++t) {
            if (t <= n) {
                float v = kd[n - t] + ((t == n) ? Dh : 0.f);
                unsigned short h0 = f2b(v);
                klh[t] = (short)h0;
                kll[t] = (short)f2b(v - b2f(h0));
            } else { klh[t] = 0; kll[t] = 0; }
        }
    }
}

// ---------------- fused: conv(+D)(GEMM) + 4x[S(GEMM)->scan->corr(GEMM)] ----
// block=(b,h); 4 waves; wave w owns c-rows [64w,64w+64); 32KB LDS, 4 blk/CU
__global__ __launch_bounds__(256, 4) void k_fused(const float* __restrict__ u,
        const int* __restrict__ length,
        const float* __restrict__ rLtab, const float* __restrict__ rL2tab,
        const short* __restrict__ Qh,
        const short* __restrict__ Pmh, const short* __restrict__ Pml,
        const short* __restrict__ Klh, const short* __restrict__ Kll,
        bf16* __restrict__ y, double* __restrict__ stats)
{
    __shared__ __align__(16) unsigned char lds[32768];  // S quarter f32 [c=256][32] (128B rows)
    int bh = blockIdx.x;
    int b = bh >> 6, h = bh & 63;
    int tid = threadIdx.x;
    int w = tid >> 6, lane = tid & 63;
    int lo = lane & 15, hi = lane >> 4;
    int len = length[b];
    const float* ub = u + (size_t)bh * 16384;

    // ---- X fragments, hi+lo split (masked u)
    s16x8 xh[4][2], xl[4][2];
    #pragma unroll
    for (int ct = 0; ct < 4; ++ct) {
        int c = w * 64 + ct * 16 + lo;
        #pragma unroll
        for (int kt = 0; kt < 2; ++kt) {
            int gidx = c * 64 + kt * 32 + hi * 8;
            float4 v0 = *(const float4*)(ub + gidx);
            float4 v1 = *(const float4*)(ub + gidx + 4);
            float xv[8] = {v0.x, v0.y, v0.z, v0.w, v1.x, v1.y, v1.z, v1.w};
            s16x8 fh, fl;
            #pragma unroll
            for (int e = 0; e < 8; ++e) {
                float xm = (gidx + e < len) ? xv[e] : 0.f;
                unsigned short h0 = f2b(xm);
                fh[e] = (short)h0;
                fl[e] = (short)f2b(xm - b2f(h0));
            }
            xh[ct][kt] = fh;
            xl[ct][kt] = fl;
        }
    }

    // ---- local conv (+ D*u via baked diagonal): Y[c][j] += X[c][t]*Kl'[t][j]
    f32x4 acc[4][4];
    #pragma unroll
    for (int ct = 0; ct < 4; ++ct)
        #pragma unroll
        for (int jt = 0; jt < 4; ++jt)
            acc[ct][jt] = f32x4{0.f, 0.f, 0.f, 0.f};
    {
        const short* klhb = Klh + (size_t)h * 4096;
        const short* kllb = Kll + (size_t)h * 4096;
        #pragma unroll
        for (int kt = 0; kt < 2; ++kt) {
            #pragma unroll
            for (int jt = 0; jt < 4; ++jt) {
                s16x8 kfh = *(const s16x8*)(klhb + (jt * 16 + lo) * 64 + kt * 32 + hi * 8);
                s16x8 kfl = *(const s16x8*)(kllb + (jt * 16 + lo) * 64 + kt * 32 + hi * 8);
                #pragma unroll
                for (int ct = 0; ct < 4; ++ct) {
                    acc[ct][jt] = __builtin_amdgcn_mfma_f32_16x16x32_bf16(xh[ct][kt], kfh, acc[ct][jt], 0, 0, 0);
                    acc[ct][jt] = __builtin_amdgcn_mfma_f32_16x16x32_bf16(xh[ct][kt], kfl, acc[ct][jt], 0, 0, 0);
                    acc[ct][jt] = __builtin_amdgcn_mfma_f32_16x16x32_bf16(xl[ct][kt], kfh, acc[ct][jt], 0, 0, 0);
                }
            }
        }
    }

    // ---- 4 quarters of 16 complex modes: GEMM1 -> scan -> GEMM3
    for (int q = 0; q < 4; ++q) {
        {   // GEMM1: S[n2q][c] = Q[n2][t] * X[c][t] -> f32 LDS
            const short* qb = Qh + (size_t)h * 8192 + (q * 32) * 64;
            #pragma unroll
            for (int mtq = 0; mtq < 2; ++mtq) {
                s16x8 q0 = *(const s16x8*)(qb + (mtq * 16 + lo) * 64 + hi * 8);
                s16x8 q1 = *(const s16x8*)(qb + (mtq * 16 + lo) * 64 + 32 + hi * 8);
                #pragma unroll
                for (int ct = 0; ct < 4; ++ct) {
                    f32x4 sc = f32x4{0.f, 0.f, 0.f, 0.f};
                    sc = __builtin_amdgcn_mfma_f32_16x16x32_bf16(q0, xh[ct][0], sc, 0, 0, 0);
                    sc = __builtin_amdgcn_mfma_f32_16x16x32_bf16(q1, xh[ct][1], sc, 0, 0, 0);
                    sc = __builtin_amdgcn_mfma_f32_16x16x32_bf16(q0, xl[ct][0], sc, 0, 0, 0);
                    sc = __builtin_amdgcn_mfma_f32_16x16x32_bf16(q1, xl[ct][1], sc, 0, 0, 0);
                    int c = w * 64 + ct * 16 + lo;
                    *(f32x4*)(lds + c * 128 + ((mtq * 64 + hi * 16) ^ SWZ(c))) = sc;
                }
            }
        }
        __syncthreads();
        // scan: wave 0; mode m=lane&15, segment s4=lane>>4 (64 chunks each).
        // In-place carry writes (byte 4m) alias the S float2 (byte 8*(m/2)) of
        // another lane in the SAME row; safety = read-before-write instruction
        // order within the wave. Pass 2 is software-pipelined (prefetch row
        // c+1, then write row c) and the order is pinned by sched_barrier(0).
        if (tid < 64) {
            int m = lane & 15, s4 = lane >> 4;
            int gm = (h * 64 + q * 16 + m) * 2;
            float r64re = rLtab[gm],  r64im = rLtab[gm + 1];
            float rKre  = rL2tab[gm], rKim  = rL2tab[gm + 1];
            float ere = 0.f, eim = 0.f;                 // pass 1: segment end-state
            for (int i = 0; i < 64; ++i) {
                int c = 64 * s4 + i;
                float2 v = *(const float2*)(lds + c * 128 + ((8 * m) ^ SWZ(c)));
                float nre = fmaf(r64re, ere, fmaf(-r64im, eim, v.x));
                eim = fmaf(r64re, eim, fmaf(r64im, ere, v.y));
                ere = nre;
            }
            float cire = 0.f, ciim = 0.f;               // exclusive prefix over segs
            #pragma unroll
            for (int k = 0; k < 3; ++k) {
                float Er = __shfl(ere, m + 16 * k, 64);
                float Ei = __shfl(eim, m + 16 * k, 64);
                if (k < s4) {
                    float nre = fmaf(rKre, cire, fmaf(-rKim, ciim, Er));
                    ciim = fmaf(rKre, ciim, fmaf(rKim, cire, Ei));
                    cire = nre;
                }
            }
            // pass 2: prefetch next row's S, then write this row's bf16 carry
            float2 v = *(const float2*)(lds + (64 * s4) * 128 + ((8 * m) ^ SWZ(64 * s4)));
            for (int i = 0; i < 64; ++i) {
                int c = 64 * s4 + i;
                int cn = (i < 63) ? c + 1 : c;          // in-bounds dummy at tail
                float2 vn = *(const float2*)(lds + cn * 128 + ((8 * m) ^ SWZ(cn)));
                __builtin_amdgcn_sched_barrier(0);      // pin read-before-write
                *(unsigned int*)(lds + c * 128 + ((4 * m) ^ SWZ(c))) =
                    (unsigned)f2b(cire) | ((unsigned)f2b(ciim) << 16);
                float nre = fmaf(r64re, cire, fmaf(-r64im, ciim, v.x));
                ciim = fmaf(r64re, ciim, fmaf(r64im, cire, v.y));
                cire = nre;
                v = vn;
            }
        }
        __syncthreads();
        {   // GEMM3: Y[c][j] += carry[c][n2q] * Pm[32q+n2q][j]
            const short* pmhb = Pmh + (size_t)h * 8192 + q * 32;
            const short* pmlb = Pml + (size_t)h * 8192 + q * 32;
            s16x8 af[4];
            #pragma unroll
            for (int ct = 0; ct < 4; ++ct) {
                int c = w * 64 + ct * 16 + lo;
                af[ct] = *(const s16x8*)(lds + c * 128 + ((16 * hi) ^ SWZ(c)));
            }
            #pragma unroll
            for (int jt = 0; jt < 4; ++jt) {
                s16x8 pfh = *(const s16x8*)(pmhb + (jt * 16 + lo) * 128 + hi * 8);
                s16x8 pfl = *(const s16x8*)(pmlb + (jt * 16 + lo) * 128 + hi * 8);
                #pragma unroll
                for (int ct = 0; ct < 4; ++ct) {
                    acc[ct][jt] = __builtin_amdgcn_mfma_f32_16x16x32_bf16(af[ct], pfh, acc[ct][jt], 0, 0, 0);
                    acc[ct][jt] = __builtin_amdgcn_mfma_f32_16x16x32_bf16(af[ct], pfl, acc[ct][jt], 0, 0, 0);
                }
            }
        }
        __syncthreads();
    }

    // ---- Y staging: acc -> bf16 [c=256][j=64] (128B rows), single rounding
    #pragma unroll
    for (int ct = 0; ct < 4; ++ct) {
        #pragma unroll
        for (int jt = 0; jt < 4; ++jt) {
            int j = jt * 16 + lo;
            #pragma unroll
            for (int rg = 0; rg < 4; ++rg) {
                int c = w * 64 + ct * 16 + hi * 4 + rg;
                *(unsigned short*)(lds + c * 128 + ((2 * j) ^ SWZ(c))) = f2b(acc[ct][jt][rg]);
            }
        }
    }
    __syncthreads();

    // ---- epilogue: mask, coalesced y store, f32 stats -> f64 atomics
    float s1 = 0.f, s2 = 0.f;
    short* yg = (short*)y + (size_t)bh * 16384;
    #pragma unroll
    for (int k = 0; k < 8; ++k) {
        int eidx = (k * 256 + tid) * 8;
        int row = eidx >> 6;
        int byt = ((eidx & 63) * 2) ^ SWZ(row);
        s16x8 yv = *(const s16x8*)(lds + row * 128 + byt);
        s16x8 o;
        #pragma unroll
        for (int e = 0; e < 8; ++e) {
            float vv = b2f((unsigned short)yv[e]);
            vv = (eidx + e < len) ? vv : 0.f;
            o[e] = (short)f2b(vv);
            s1 += vv;
            s2 = fmaf(vv, vv, s2);
        }
        *(s16x8*)(yg + eidx) = o;
    }
    #pragma unroll
    for (int off = 32; off > 0; off >>= 1) {
        s1 += __shfl_down(s1, off, 64);
        s2 += __shfl_down(s2, off, 64);
    }
    if (lane == 0) {
        atomicAdd(&stats[2 * h],     (double)s1);
        atomicAdd(&stats[2 * h + 1], (double)s2);
    }
}

// ---------------- K4: layernorm + FiLM + tanh + residual (8 elems/thread) --
__global__ __launch_bounds__(256) void k4_final(const float* __restrict__ u,
        const bf16* __restrict__ y, const float* __restrict__ cond,
        const float* __restrict__ fw, const float* __restrict__ fb,
        const double* __restrict__ stats, float* __restrict__ out)
{
    int tid = threadIdx.x;
    size_t idx8 = ((size_t)blockIdx.x * 256 + tid) * 8;
    int bh = (int)(idx8 >> 14);
    int b = bh >> 6, h = bh & 63;
    __shared__ float gg[2];
    if (tid == 0) {
        float g = fb[h], bb = fb[64 + h];
        #pragma unroll
        for (int k = 0; k < 3; ++k) {
            g  = fmaf(cond[b * 3 + k], fw[h * 3 + k], g);
            bb = fmaf(cond[b * 3 + k], fw[(64 + h) * 3 + k], bb);
        }
        gg[0] = g; gg[1] = bb;
    }
    __syncthreads();
    double inv = 1.0 / (16.0 * 16384.0);
    double mean_d = stats[2 * h] * inv;
    double var_d  = stats[2 * h + 1] * inv - mean_d * mean_d;
    float mean = (float)mean_d;
    float rstd = rsqrtf((float)var_d + 1e-5f);
    float gv = gg[0], bv = gg[1];
    float4 u0 = *(const float4*)(u + idx8);
    float4 u1 = *(const float4*)(u + idx8 + 4);
    s16x8 yv = *(const s16x8*)((const short*)y + idx8);
    float uv[8] = {u0.x, u0.y, u0.z, u0.w, u1.x, u1.y, u1.z, u1.w};
    float ov[8];
    #pragma unroll
    for (int e = 0; e < 8; ++e) {
        float z = fmaf((b2f((unsigned short)yv[e]) - mean) * rstd, gv, bv);
        ov[e] = uv[e] + tanhf(z);
    }
    *(float4*)(out + idx8)     = float4{ov[0], ov[1], ov[2], ov[3]};
    *(float4*)(out + idx8 + 4) = float4{ov[4], ov[5], ov[6], ov[7]};
}

// ---------------------------------------------------------------------------
extern "C" void kernel_launch(void* const* d_in, const int* in_sizes, int n_in,
                              void* d_out, int out_size, void* d_ws, size_t ws_size,
                              hipStream_t stream)
{
    const float* u           = (const float*)d_in[0];
    const float* cond        = (const float*)d_in[1];
    const int*   length      = (const int*)  d_in[2];
    const float* log_dt      = (const float*)d_in[3];
    const float* C_ri        = (const float*)d_in[4];
    const float* log_A_real  = (const float*)d_in[5];
    const float* A_imag      = (const float*)d_in[6];
    const float* D           = (const float*)d_in[7];
    const float* film_w      = (const float*)d_in[8];
    const float* film_b      = (const float*)d_in[9];
    float* out = (float*)d_out;

    char* w = (char*)d_ws;
    bf16*   y      = (bf16*)w;                    // 33,554,432 B
    short*  Qh     = (short*)(w + 33554432);      //  1,048,576 B
    short*  Pmh    = (short*)(w + 34603008);      //  1,048,576 B
    short*  Pml    = (short*)(w + 35651584);      //  1,048,576 B
    short*  Klh    = (short*)(w + 36700160);      //    524,288 B
    short*  Kll    = (short*)(w + 37224448);      //    524,288 B
    float*  rLtab  = (float*)(w + 37748736);      //     32,768 B
    float*  rL2tab = (float*)(w + 37781504);      //     32,768 B
    double* stats  = (double*)(w + 37814272);     //      1,024 B   (~37.8 MB)

    hipMemsetAsync(stats, 0, 1024, stream);
    hipLaunchKernelGGL(k0_setup, dim3(64),   dim3(256), 0, stream,
                       log_dt, C_ri, log_A_real, A_imag, D,
                       rLtab, rL2tab, Qh, Pmh, Pml, Klh, Kll);
    hipLaunchKernelGGL(k_fused,  dim3(1024), dim3(256), 0, stream,
                       u, length, rLtab, rL2tab, Qh, Pmh, Pml, Klh, Kll, y, stats);
    hipLaunchKernelGGL(k4_final, dim3(8192), dim3(256), 0, stream,
                       u, y, cond, film_w, film_b, stats, out);
}

// Round 7
// 131.491 us; speedup vs baseline: 1.4668x; 1.4668x over previous
//
#include <hip/hip_runtime.h>
#include <hip/hip_bf16.h>

typedef __hip_bfloat16 bf16;
typedef __attribute__((ext_vector_type(8))) short s16x8;
typedef __attribute__((ext_vector_type(4))) float f32x4;

#define SWZ(c) ((((c) ^ ((c) >> 3)) & 7) << 4)   // 128B-row swizzle, XOR bits 4-6

__device__ __forceinline__ unsigned short f2b(float x){
    __hip_bfloat16 h = __float2bfloat16(x);
    return __builtin_bit_cast(unsigned short, h);
}
__device__ __forceinline__ float b2f(unsigned short s){
    unsigned int u = (unsigned int)s << 16;
    return __builtin_bit_cast(float, u);
}

// ---------------- K0: per-h tables via direct complex exp ------------------
// Qh[h][n2=128][t=64]     : Q[2n][t]=Re r^{63-t}, Q[2n+1][t]=Im r^{63-t} (bf16)
// Pmh/Pml[h][j=64][n2=128]: Pm[j][2n]=Re(2Ck r^{j+1}), [2n+1]=-Im(...)   (hi+lo)
// Klh/Kll[h][j=64][t=64]  : Kd[j-t] (t<=j) + D*delta(t==j)  [row j]      (hi+lo)
// rLtab[h][n][2]=r^64 ; rL2tab[h][n][2]=r^4096  (f32, scan)
__global__ __launch_bounds__(256) void k0_setup(const float* __restrict__ log_dt,
        const float* __restrict__ C_ri, const float* __restrict__ log_A_real,
        const float* __restrict__ A_imag, const float* __restrict__ Dp,
        float* __restrict__ rLtab, float* __restrict__ rL2tab,
        short* __restrict__ Qh,
        short* __restrict__ Pmh, short* __restrict__ Pml,
        short* __restrict__ Klh, short* __restrict__ Kll)
{
    __shared__ float arr[64][65];   // Pm_re staging: arr[j][n] = Re(2Ck r^{j+1})
    __shared__ float a0[64];        // 2*Re(Ck)
    __shared__ float kd[64];
    int h = blockIdx.x;
    int tid = threadIdx.x;
    int n = tid & 63, g = tid >> 6;
    int hn = h * 64 + n;
    double dtd  = exp((double)log_dt[h]);
    float  Aref = -expf(log_A_real[hn]);
    double Ared = (double)Aref;
    double Aimd = (double)A_imag[hn];
    double adt  = Aimd * dtd;                 // angle per unit exponent
    float  mdt  = (float)(Ared * dtd);        // log-magnitude per unit exponent
    // cexp(e) = r^e
    auto cexp = [&](float e, float& re, float& im){
        double a = adt * (double)e;
        double k = floor(a * 0.15915494309189535);
        float ang = (float)(a - k * 6.283185307179586);
        float si, co;
        __sincosf(ang, &si, &co);
        float mag = expf(mdt * e);
        re = mag * co; im = mag * si;
    };
    // Ck = C * (r-1)/A
    float rre, rim; cexp(1.f, rre, rim);
    float Cre = C_ri[2 * hn], Cim = C_ri[2 * hn + 1];
    float emre = rre - 1.f, emim = rim;
    float inva2 = 1.f / (Aref * Aref + (float)(Aimd * Aimd));
    float qre_ = (emre * Aref + emim * (float)Aimd) * inva2;
    float qim_ = (emim * Aref - emre * (float)Aimd) * inva2;
    float ckre = Cre * qre_ - Cim * qim_;
    float ckim = Cre * qim_ + Cim * qre_;
    // Q rows 2n,2n+1 for t in [16g,16g+16)
    {
        short* q0 = Qh + (size_t)h * 8192 + (2 * n) * 64;
        short* q1 = q0 + 64;
        for (int t = 16 * g; t < 16 * g + 16; ++t) {
            float pre, pim; cexp((float)(63 - t), pre, pim);
            q0[t] = (short)f2b(pre);
            q1[t] = (short)f2b(pim);
        }
    }
    if (g == 0) {   // r^64
        float pre, pim; cexp(64.f, pre, pim);
        rLtab[2 * hn] = pre; rLtab[2 * hn + 1] = pim;
    }
    if (g == 1) {   // r^4096
        float pre, pim; cexp(4096.f, pre, pim);
        rL2tab[2 * hn] = pre; rL2tab[2 * hn + 1] = pim;
    }
    if (g == 2) a0[n] = 2.f * ckre;
    // Pm rows j in [16g,16g+16)
    {
        short* pmh = Pmh + (size_t)h * 8192;
        short* pml = Pml + (size_t)h * 8192;
        for (int j = 16 * g; j < 16 * g + 16; ++j) {
            float pre, pim; cexp((float)(j + 1), pre, pim);
            float wre = 2.f * (ckre * pre - ckim * pim);
            float wim = 2.f * (ckre * pim + ckim * pre);
            unsigned short h0 = f2b(wre), h1 = f2b(-wim);
            pmh[j * 128 + 2 * n]     = (short)h0;
            pml[j * 128 + 2 * n]     = (short)f2b(wre - b2f(h0));
            pmh[j * 128 + 2 * n + 1] = (short)h1;
            pml[j * 128 + 2 * n + 1] = (short)f2b(-wim - b2f(h1));
            arr[j][n] = wre;
        }
    }
    __syncthreads();
    if (tid < 64) {                 // Kd[d]
        int d = tid;
        float s = 0.f;
        if (d == 0) { for (int k = 0; k < 64; ++k) s += a0[k]; }
        else        { for (int k = 0; k < 64; ++k) s += arr[d - 1][k]; }
        kd[d] = s;
    }
    __syncthreads();
    // Klow ROW j=n (storage [j][t], R4-proven layout), D on diagonal
    {
        float Dh = Dp[h];
        short* klh = Klh + (size_t)h * 4096 + n * 64;   // row j=n
        short* kll = Kll + (size_t)h * 4096 + n * 64;
        for (int t = 16 * g; t < 16 * g + 16; ++t) {
            if (t <= n) {
                float v = kd[n - t] + ((t == n) ? Dh : 0.f);
                unsigned short h0 = f2b(v);
                klh[t] = (short)h0;
                kll[t] = (short)f2b(v - b2f(h0));
            } else { klh[t] = 0; kll[t] = 0; }
        }
    }
}

// ---------------- fused: conv(+D)(GEMM) + 4x[S(GEMM)->scan->corr(GEMM)] ----
// block=(b,h); 4 waves; wave w owns c-rows [64w,64w+64); 32KB LDS.
// __launch_bounds__(256,2): 2 blocks/CU, VGPR cap 256 -> NO spills (R6 post-
// mortem: (256,4) capped unified RF at 128, spilled xh/xl/acc -> 400MB scratch).
__global__ __launch_bounds__(256, 2) void k_fused(const float* __restrict__ u,
        const int* __restrict__ length,
        const float* __restrict__ rLtab, const float* __restrict__ rL2tab,
        const short* __restrict__ Qh,
        const short* __restrict__ Pmh, const short* __restrict__ Pml,
        const short* __restrict__ Klh, const short* __restrict__ Kll,
        bf16* __restrict__ y, double* __restrict__ stats)
{
    __shared__ __align__(16) unsigned char lds[32768];  // S quarter f32 [c=256][32] (128B rows)
    int bh = blockIdx.x;
    int b = bh >> 6, h = bh & 63;
    int tid = threadIdx.x;
    int w = tid >> 6, lane = tid & 63;
    int lo = lane & 15, hi = lane >> 4;
    int len = length[b];
    const float* ub = u + (size_t)bh * 16384;

    // ---- X fragments, hi+lo split (masked u)
    s16x8 xh[4][2], xl[4][2];
    #pragma unroll
    for (int ct = 0; ct < 4; ++ct) {
        int c = w * 64 + ct * 16 + lo;
        #pragma unroll
        for (int kt = 0; kt < 2; ++kt) {
            int gidx = c * 64 + kt * 32 + hi * 8;
            float4 v0 = *(const float4*)(ub + gidx);
            float4 v1 = *(const float4*)(ub + gidx + 4);
            float xv[8] = {v0.x, v0.y, v0.z, v0.w, v1.x, v1.y, v1.z, v1.w};
            s16x8 fh, fl;
            #pragma unroll
            for (int e = 0; e < 8; ++e) {
                float xm = (gidx + e < len) ? xv[e] : 0.f;
                unsigned short h0 = f2b(xm);
                fh[e] = (short)h0;
                fl[e] = (short)f2b(xm - b2f(h0));
            }
            xh[ct][kt] = fh;
            xl[ct][kt] = fl;
        }
    }

    // ---- local conv (+ D*u via baked diagonal): Y[c][j] += X[c][t]*Kl'[t][j]
    f32x4 acc[4][4];
    #pragma unroll
    for (int ct = 0; ct < 4; ++ct)
        #pragma unroll
        for (int jt = 0; jt < 4; ++jt)
            acc[ct][jt] = f32x4{0.f, 0.f, 0.f, 0.f};
    {
        const short* klhb = Klh + (size_t)h * 4096;
        const short* kllb = Kll + (size_t)h * 4096;
        #pragma unroll
        for (int kt = 0; kt < 2; ++kt) {
            #pragma unroll
            for (int jt = 0; jt < 4; ++jt) {
                s16x8 kfh = *(const s16x8*)(klhb + (jt * 16 + lo) * 64 + kt * 32 + hi * 8);
                s16x8 kfl = *(const s16x8*)(kllb + (jt * 16 + lo) * 64 + kt * 32 + hi * 8);
                #pragma unroll
                for (int ct = 0; ct < 4; ++ct) {
                    acc[ct][jt] = __builtin_amdgcn_mfma_f32_16x16x32_bf16(xh[ct][kt], kfh, acc[ct][jt], 0, 0, 0);
                    acc[ct][jt] = __builtin_amdgcn_mfma_f32_16x16x32_bf16(xh[ct][kt], kfl, acc[ct][jt], 0, 0, 0);
                    acc[ct][jt] = __builtin_amdgcn_mfma_f32_16x16x32_bf16(xl[ct][kt], kfh, acc[ct][jt], 0, 0, 0);
                }
            }
        }
    }

    // ---- 4 quarters of 16 complex modes: GEMM1 -> scan -> GEMM3
    for (int q = 0; q < 4; ++q) {
        {   // GEMM1: S[n2q][c] = Q[n2][t] * X[c][t] -> f32 LDS
            const short* qb = Qh + (size_t)h * 8192 + (q * 32) * 64;
            #pragma unroll
            for (int mtq = 0; mtq < 2; ++mtq) {
                s16x8 q0 = *(const s16x8*)(qb + (mtq * 16 + lo) * 64 + hi * 8);
                s16x8 q1 = *(const s16x8*)(qb + (mtq * 16 + lo) * 64 + 32 + hi * 8);
                #pragma unroll
                for (int ct = 0; ct < 4; ++ct) {
                    f32x4 sc = f32x4{0.f, 0.f, 0.f, 0.f};
                    sc = __builtin_amdgcn_mfma_f32_16x16x32_bf16(q0, xh[ct][0], sc, 0, 0, 0);
                    sc = __builtin_amdgcn_mfma_f32_16x16x32_bf16(q1, xh[ct][1], sc, 0, 0, 0);
                    sc = __builtin_amdgcn_mfma_f32_16x16x32_bf16(q0, xl[ct][0], sc, 0, 0, 0);
                    sc = __builtin_amdgcn_mfma_f32_16x16x32_bf16(q1, xl[ct][1], sc, 0, 0, 0);
                    int c = w * 64 + ct * 16 + lo;
                    *(f32x4*)(lds + c * 128 + ((mtq * 64 + hi * 16) ^ SWZ(c))) = sc;
                }
            }
        }
        __syncthreads();
        // scan: wave 0; mode m=lane&15, segment s4=lane>>4 (64 chunks each).
        // In-place carry writes (byte 4m) alias the S float2 (byte 8*(m/2)) of
        // another lane in the SAME row; safety = read-before-write instruction
        // order within the wave. Pass 2 is software-pipelined (prefetch row
        // c+1, then write row c) and the order is pinned by sched_barrier(0).
        if (tid < 64) {
            int m = lane & 15, s4 = lane >> 4;
            int gm = (h * 64 + q * 16 + m) * 2;
            float r64re = rLtab[gm],  r64im = rLtab[gm + 1];
            float rKre  = rL2tab[gm], rKim  = rL2tab[gm + 1];
            float ere = 0.f, eim = 0.f;                 // pass 1: segment end-state
            for (int i = 0; i < 64; ++i) {
                int c = 64 * s4 + i;
                float2 v = *(const float2*)(lds + c * 128 + ((8 * m) ^ SWZ(c)));
                float nre = fmaf(r64re, ere, fmaf(-r64im, eim, v.x));
                eim = fmaf(r64re, eim, fmaf(r64im, ere, v.y));
                ere = nre;
            }
            float cire = 0.f, ciim = 0.f;               // exclusive prefix over segs
            #pragma unroll
            for (int k = 0; k < 3; ++k) {
                float Er = __shfl(ere, m + 16 * k, 64);
                float Ei = __shfl(eim, m + 16 * k, 64);
                if (k < s4) {
                    float nre = fmaf(rKre, cire, fmaf(-rKim, ciim, Er));
                    ciim = fmaf(rKre, ciim, fmaf(rKim, cire, Ei));
                    cire = nre;
                }
            }
            // pass 2: prefetch next row's S, then write this row's bf16 carry
            float2 v = *(const float2*)(lds + (64 * s4) * 128 + ((8 * m) ^ SWZ(64 * s4)));
            for (int i = 0; i < 64; ++i) {
                int c = 64 * s4 + i;
                int cn = (i < 63) ? c + 1 : c;          // in-bounds dummy at tail
                float2 vn = *(const float2*)(lds + cn * 128 + ((8 * m) ^ SWZ(cn)));
                __builtin_amdgcn_sched_barrier(0);      // pin read-before-write
                *(unsigned int*)(lds + c * 128 + ((4 * m) ^ SWZ(c))) =
                    (unsigned)f2b(cire) | ((unsigned)f2b(ciim) << 16);
                float nre = fmaf(r64re, cire, fmaf(-r64im, ciim, v.x));
                ciim = fmaf(r64re, ciim, fmaf(r64im, cire, v.y));
                cire = nre;
                v = vn;
            }
        }
        __syncthreads();
        {   // GEMM3: Y[c][j] += carry[c][n2q] * Pm[32q+n2q][j]
            const short* pmhb = Pmh + (size_t)h * 8192 + q * 32;
            const short* pmlb = Pml + (size_t)h * 8192 + q * 32;
            s16x8 af[4];
            #pragma unroll
            for (int ct = 0; ct < 4; ++ct) {
                int c = w * 64 + ct * 16 + lo;
                af[ct] = *(const s16x8*)(lds + c * 128 + ((16 * hi) ^ SWZ(c)));
            }
            #pragma unroll
            for (int jt = 0; jt < 4; ++jt) {
                s16x8 pfh = *(const s16x8*)(pmhb + (jt * 16 + lo) * 128 + hi * 8);
                s16x8 pfl = *(const s16x8*)(pmlb + (jt * 16 + lo) * 128 + hi * 8);
                #pragma unroll
                for (int ct = 0; ct < 4; ++ct) {
                    acc[ct][jt] = __builtin_amdgcn_mfma_f32_16x16x32_bf16(af[ct], pfh, acc[ct][jt], 0, 0, 0);
                    acc[ct][jt] = __builtin_amdgcn_mfma_f32_16x16x32_bf16(af[ct], pfl, acc[ct][jt], 0, 0, 0);
                }
            }
        }
        __syncthreads();
    }

    // ---- Y staging: acc -> bf16 [c=256][j=64] (128B rows), single rounding
    #pragma unroll
    for (int ct = 0; ct < 4; ++ct) {
        #pragma unroll
        for (int jt = 0; jt < 4; ++jt) {
            int j = jt * 16 + lo;
            #pragma unroll
            for (int rg = 0; rg < 4; ++rg) {
                int c = w * 64 + ct * 16 + hi * 4 + rg;
                *(unsigned short*)(lds + c * 128 + ((2 * j) ^ SWZ(c))) = f2b(acc[ct][jt][rg]);
            }
        }
    }
    __syncthreads();

    // ---- epilogue: mask, coalesced y store, f32 stats -> f64 atomics
    float s1 = 0.f, s2 = 0.f;
    short* yg = (short*)y + (size_t)bh * 16384;
    #pragma unroll
    for (int k = 0; k < 8; ++k) {
        int eidx = (k * 256 + tid) * 8;
        int row = eidx >> 6;
        int byt = ((eidx & 63) * 2) ^ SWZ(row);
        s16x8 yv = *(const s16x8*)(lds + row * 128 + byt);
        s16x8 o;
        #pragma unroll
        for (int e = 0; e < 8; ++e) {
            float vv = b2f((unsigned short)yv[e]);
            vv = (eidx + e < len) ? vv : 0.f;
            o[e] = (short)f2b(vv);
            s1 += vv;
            s2 = fmaf(vv, vv, s2);
        }
        *(s16x8*)(yg + eidx) = o;
    }
    #pragma unroll
    for (int off = 32; off > 0; off >>= 1) {
        s1 += __shfl_down(s1, off, 64);
        s2 += __shfl_down(s2, off, 64);
    }
    if (lane == 0) {
        atomicAdd(&stats[2 * h],     (double)s1);
        atomicAdd(&stats[2 * h + 1], (double)s2);
    }
}

// ---------------- K4: layernorm + FiLM + tanh + residual (8 elems/thread) --
__global__ __launch_bounds__(256) void k4_final(const float* __restrict__ u,
        const bf16* __restrict__ y, const float* __restrict__ cond,
        const float* __restrict__ fw, const float* __restrict__ fb,
        const double* __restrict__ stats, float* __restrict__ out)
{
    int tid = threadIdx.x;
    size_t idx8 = ((size_t)blockIdx.x * 256 + tid) * 8;
    int bh = (int)(idx8 >> 14);
    int b = bh >> 6, h = bh & 63;
    __shared__ float gg[2];
    if (tid == 0) {
        float g = fb[h], bb = fb[64 + h];
        #pragma unroll
        for (int k = 0; k < 3; ++k) {
            g  = fmaf(cond[b * 3 + k], fw[h * 3 + k], g);
            bb = fmaf(cond[b * 3 + k], fw[(64 + h) * 3 + k], bb);
        }
        gg[0] = g; gg[1] = bb;
    }
    __syncthreads();
    double inv = 1.0 / (16.0 * 16384.0);
    double mean_d = stats[2 * h] * inv;
    double var_d  = stats[2 * h + 1] * inv - mean_d * mean_d;
    float mean = (float)mean_d;
    float rstd = rsqrtf((float)var_d + 1e-5f);
    float gv = gg[0], bv = gg[1];
    float4 u0 = *(const float4*)(u + idx8);
    float4 u1 = *(const float4*)(u + idx8 + 4);
    s16x8 yv = *(const s16x8*)((const short*)y + idx8);
    float uv[8] = {u0.x, u0.y, u0.z, u0.w, u1.x, u1.y, u1.z, u1.w};
    float ov[8];
    #pragma unroll
    for (int e = 0; e < 8; ++e) {
        float z = fmaf((b2f((unsigned short)yv[e]) - mean) * rstd, gv, bv);
        ov[e] = uv[e] + tanhf(z);
    }
    *(float4*)(out + idx8)     = float4{ov[0], ov[1], ov[2], ov[3]};
    *(float4*)(out + idx8 + 4) = float4{ov[4], ov[5], ov[6], ov[7]};
}

// ---------------------------------------------------------------------------
extern "C" void kernel_launch(void* const* d_in, const int* in_sizes, int n_in,
                              void* d_out, int out_size, void* d_ws, size_t ws_size,
                              hipStream_t stream)
{
    const float* u           = (const float*)d_in[0];
    const float* cond        = (const float*)d_in[1];
    const int*   length      = (const int*)  d_in[2];
    const float* log_dt      = (const float*)d_in[3];
    const float* C_ri        = (const float*)d_in[4];
    const float* log_A_real  = (const float*)d_in[5];
    const float* A_imag      = (const float*)d_in[6];
    const float* D           = (const float*)d_in[7];
    const float* film_w      = (const float*)d_in[8];
    const float* film_b      = (const float*)d_in[9];
    float* out = (float*)d_out;

    char* w = (char*)d_ws;
    bf16*   y      = (bf16*)w;                    // 33,554,432 B
    short*  Qh     = (short*)(w + 33554432);      //  1,048,576 B
    short*  Pmh    = (short*)(w + 34603008);      //  1,048,576 B
    short*  Pml    = (short*)(w + 35651584);      //  1,048,576 B
    short*  Klh    = (short*)(w + 36700160);      //    524,288 B
    short*  Kll    = (short*)(w + 37224448);      //    524,288 B
    float*  rLtab  = (float*)(w + 37748736);      //     32,768 B
    float*  rL2tab = (float*)(w + 37781504);      //     32,768 B
    double* stats  = (double*)(w + 37814272);     //      1,024 B   (~37.8 MB)

    hipMemsetAsync(stats, 0, 1024, stream);
    hipLaunchKernelGGL(k0_setup, dim3(64),   dim3(256), 0, stream,
                       log_dt, C_ri, log_A_real, A_imag, D,
                       rLtab, rL2tab, Qh, Pmh, Pml, Klh, Kll);
    hipLaunchKernelGGL(k_fused,  dim3(1024), dim3(256), 0, stream,
                       u, length, rLtab, rL2tab, Qh, Pmh, Pml, Klh, Kll, y, stats);
    hipLaunchKernelGGL(k4_final, dim3(8192), dim3(256), 0, stream,
                       u, y, cond, film_w, film_b, stats, out);
}

// Round 8
// 114.444 us; speedup vs baseline: 1.6853x; 1.1490x over previous
//
#include <hip/hip_runtime.h>
#include <hip/hip_bf16.h>

typedef __hip_bfloat16 bf16;
typedef __attribute__((ext_vector_type(8))) short s16x8;
typedef __attribute__((ext_vector_type(4))) float f32x4;

#define SWZ(c) ((((c) ^ ((c) >> 3)) & 7) << 4)   // 128B-row swizzle, XOR bits 4-6

__device__ __forceinline__ unsigned short f2b(float x){
    __hip_bfloat16 h = __float2bfloat16(x);
    return __builtin_bit_cast(unsigned short, h);
}
__device__ __forceinline__ float b2f(unsigned short s){
    unsigned int u = (unsigned int)s << 16;
    return __builtin_bit_cast(float, u);
}

// ---------------- K0: per-h tables via direct complex exp ------------------
// Qh[h][n2=128][t=64]     : Q[2n][t]=Re r^{63-t}, Q[2n+1][t]=Im r^{63-t} (bf16)
// Pmh/Pml[h][j=64][n2=128]: Pm[j][2n]=Re(2Ck r^{j+1}), [2n+1]=-Im(...)   (hi+lo)
// Klh/Kll[h][j=64][t=64]  : Kd[j-t] (t<=j) + D*delta(t==j)  [row j]      (hi+lo)
// rLtab[h][n][2]=r^64 ; rStab[h][n][2]=r^1024  (f32, scan)
__global__ __launch_bounds__(256) void k0_setup(const float* __restrict__ log_dt,
        const float* __restrict__ C_ri, const float* __restrict__ log_A_real,
        const float* __restrict__ A_imag, const float* __restrict__ Dp,
        float* __restrict__ rLtab, float* __restrict__ rStab,
        short* __restrict__ Qh,
        short* __restrict__ Pmh, short* __restrict__ Pml,
        short* __restrict__ Klh, short* __restrict__ Kll)
{
    __shared__ float arr[64][65];   // Pm_re staging: arr[j][n] = Re(2Ck r^{j+1})
    __shared__ float a0[64];        // 2*Re(Ck)
    __shared__ float kd[64];
    int h = blockIdx.x;
    int tid = threadIdx.x;
    int n = tid & 63, g = tid >> 6;
    int hn = h * 64 + n;
    double dtd  = exp((double)log_dt[h]);
    float  Aref = -expf(log_A_real[hn]);
    double Ared = (double)Aref;
    double Aimd = (double)A_imag[hn];
    double adt  = Aimd * dtd;                 // angle per unit exponent
    float  mdt  = (float)(Ared * dtd);        // log-magnitude per unit exponent
    // cexp(e) = r^e
    auto cexp = [&](float e, float& re, float& im){
        double a = adt * (double)e;
        double k = floor(a * 0.15915494309189535);
        float ang = (float)(a - k * 6.283185307179586);
        float si, co;
        __sincosf(ang, &si, &co);
        float mag = expf(mdt * e);
        re = mag * co; im = mag * si;
    };
    // Ck = C * (r-1)/A
    float rre, rim; cexp(1.f, rre, rim);
    float Cre = C_ri[2 * hn], Cim = C_ri[2 * hn + 1];
    float emre = rre - 1.f, emim = rim;
    float inva2 = 1.f / (Aref * Aref + (float)(Aimd * Aimd));
    float qre_ = (emre * Aref + emim * (float)Aimd) * inva2;
    float qim_ = (emim * Aref - emre * (float)Aimd) * inva2;
    float ckre = Cre * qre_ - Cim * qim_;
    float ckim = Cre * qim_ + Cim * qre_;
    // Q rows 2n,2n+1 for t in [16g,16g+16)
    {
        short* q0 = Qh + (size_t)h * 8192 + (2 * n) * 64;
        short* q1 = q0 + 64;
        for (int t = 16 * g; t < 16 * g + 16; ++t) {
            float pre, pim; cexp((float)(63 - t), pre, pim);
            q0[t] = (short)f2b(pre);
            q1[t] = (short)f2b(pim);
        }
    }
    if (g == 0) {   // r^64
        float pre, pim; cexp(64.f, pre, pim);
        rLtab[2 * hn] = pre; rLtab[2 * hn + 1] = pim;
    }
    if (g == 1) {   // r^1024 (segment hop for the 16-segment scan)
        float pre, pim; cexp(1024.f, pre, pim);
        rStab[2 * hn] = pre; rStab[2 * hn + 1] = pim;
    }
    if (g == 2) a0[n] = 2.f * ckre;
    // Pm rows j in [16g,16g+16)
    {
        short* pmh = Pmh + (size_t)h * 8192;
        short* pml = Pml + (size_t)h * 8192;
        for (int j = 16 * g; j < 16 * g + 16; ++j) {
            float pre, pim; cexp((float)(j + 1), pre, pim);
            float wre = 2.f * (ckre * pre - ckim * pim);
            float wim = 2.f * (ckre * pim + ckim * pre);
            unsigned short h0 = f2b(wre), h1 = f2b(-wim);
            pmh[j * 128 + 2 * n]     = (short)h0;
            pml[j * 128 + 2 * n]     = (short)f2b(wre - b2f(h0));
            pmh[j * 128 + 2 * n + 1] = (short)h1;
            pml[j * 128 + 2 * n + 1] = (short)f2b(-wim - b2f(h1));
            arr[j][n] = wre;
        }
    }
    __syncthreads();
    if (tid < 64) {                 // Kd[d]
        int d = tid;
        float s = 0.f;
        if (d == 0) { for (int k = 0; k < 64; ++k) s += a0[k]; }
        else        { for (int k = 0; k < 64; ++k) s += arr[d - 1][k]; }
        kd[d] = s;
    }
    __syncthreads();
    // Klow ROW j=n (storage [j][t]), D on diagonal
    {
        float Dh = Dp[h];
        short* klh = Klh + (size_t)h * 4096 + n * 64;   // row j=n
        short* kll = Kll + (size_t)h * 4096 + n * 64;
        for (int t = 16 * g; t < 16 * g + 16; ++t) {
            if (t <= n) {
                float v = kd[n - t] + ((t == n) ? Dh : 0.f);
                unsigned short h0 = f2b(v);
                klh[t] = (short)h0;
                kll[t] = (short)f2b(v - b2f(h0));
            } else { klh[t] = 0; kll[t] = 0; }
        }
    }
}

// ---------------- fused: conv(+D)(GEMM) + 4x[S(GEMM)->scan->corr(GEMM)] ----
// block=(b,h); 4 waves; wave w owns c-rows [64w,64w+64).
// LDS: S region 32KB ([256][128B] f32) + carry region 16KB ([256][64B] bf16).
// Scan: 256 threads, 16 modes x 16 segments, Kogge-Stone combine over segments
// (r^1024 hops). Carries to the SEPARATE region -> no aliasing, no pinning.
__global__ __launch_bounds__(256, 2) void k_fused(const float* __restrict__ u,
        const int* __restrict__ length,
        const float* __restrict__ rLtab, const float* __restrict__ rStab,
        const short* __restrict__ Qh,
        const short* __restrict__ Pmh, const short* __restrict__ Pml,
        const short* __restrict__ Klh, const short* __restrict__ Kll,
        bf16* __restrict__ y, double* __restrict__ stats)
{
    __shared__ __align__(16) unsigned char lds[49152];
    unsigned char* carr = lds + 32768;
    int bh = blockIdx.x;
    int b = bh >> 6, h = bh & 63;
    int tid = threadIdx.x;
    int w = tid >> 6, lane = tid & 63;
    int lo = lane & 15, hi = lane >> 4;
    int len = length[b];
    const float* ub = u + (size_t)bh * 16384;

    // ---- X fragments, hi+lo split (masked u)
    s16x8 xh[4][2], xl[4][2];
    #pragma unroll
    for (int ct = 0; ct < 4; ++ct) {
        int c = w * 64 + ct * 16 + lo;
        #pragma unroll
        for (int kt = 0; kt < 2; ++kt) {
            int gidx = c * 64 + kt * 32 + hi * 8;
            float4 v0 = *(const float4*)(ub + gidx);
            float4 v1 = *(const float4*)(ub + gidx + 4);
            float xv[8] = {v0.x, v0.y, v0.z, v0.w, v1.x, v1.y, v1.z, v1.w};
            s16x8 fh, fl;
            #pragma unroll
            for (int e = 0; e < 8; ++e) {
                float xm = (gidx + e < len) ? xv[e] : 0.f;
                unsigned short h0 = f2b(xm);
                fh[e] = (short)h0;
                fl[e] = (short)f2b(xm - b2f(h0));
            }
            xh[ct][kt] = fh;
            xl[ct][kt] = fl;
        }
    }

    // ---- local conv (+ D*u via baked diagonal): Y[c][j] += X[c][t]*Kl'[t][j]
    f32x4 acc[4][4];
    #pragma unroll
    for (int ct = 0; ct < 4; ++ct)
        #pragma unroll
        for (int jt = 0; jt < 4; ++jt)
            acc[ct][jt] = f32x4{0.f, 0.f, 0.f, 0.f};
    {
        const short* klhb = Klh + (size_t)h * 4096;
        const short* kllb = Kll + (size_t)h * 4096;
        #pragma unroll
        for (int kt = 0; kt < 2; ++kt) {
            #pragma unroll
            for (int jt = 0; jt < 4; ++jt) {
                s16x8 kfh = *(const s16x8*)(klhb + (jt * 16 + lo) * 64 + kt * 32 + hi * 8);
                s16x8 kfl = *(const s16x8*)(kllb + (jt * 16 + lo) * 64 + kt * 32 + hi * 8);
                #pragma unroll
                for (int ct = 0; ct < 4; ++ct) {
                    acc[ct][jt] = __builtin_amdgcn_mfma_f32_16x16x32_bf16(xh[ct][kt], kfh, acc[ct][jt], 0, 0, 0);
                    acc[ct][jt] = __builtin_amdgcn_mfma_f32_16x16x32_bf16(xh[ct][kt], kfl, acc[ct][jt], 0, 0, 0);
                    acc[ct][jt] = __builtin_amdgcn_mfma_f32_16x16x32_bf16(xl[ct][kt], kfh, acc[ct][jt], 0, 0, 0);
                }
            }
        }
    }

    // GEMM1 for quarter q: S[c][n2q] f32 into the S region
    auto gemm1 = [&](int q){
        const short* qb = Qh + (size_t)h * 8192 + (q * 32) * 64;
        #pragma unroll
        for (int mtq = 0; mtq < 2; ++mtq) {
            s16x8 q0 = *(const s16x8*)(qb + (mtq * 16 + lo) * 64 + hi * 8);
            s16x8 q1 = *(const s16x8*)(qb + (mtq * 16 + lo) * 64 + 32 + hi * 8);
            #pragma unroll
            for (int ct = 0; ct < 4; ++ct) {
                f32x4 sc = f32x4{0.f, 0.f, 0.f, 0.f};
                sc = __builtin_amdgcn_mfma_f32_16x16x32_bf16(q0, xh[ct][0], sc, 0, 0, 0);
                sc = __builtin_amdgcn_mfma_f32_16x16x32_bf16(q1, xh[ct][1], sc, 0, 0, 0);
                sc = __builtin_amdgcn_mfma_f32_16x16x32_bf16(q0, xl[ct][0], sc, 0, 0, 0);
                sc = __builtin_amdgcn_mfma_f32_16x16x32_bf16(q1, xl[ct][1], sc, 0, 0, 0);
                int c = w * 64 + ct * 16 + lo;
                *(f32x4*)(lds + c * 128 + ((mtq * 64 + hi * 16) ^ SWZ(c))) = sc;
            }
        }
    };

    gemm1(0);
    for (int q = 0; q < 4; ++q) {
        __syncthreads();
        // ---- scan: thread = (mode m = tid>>4, segment s = tid&15), 16 chunks/seg
        {
            int m = tid >> 4, s = tid & 15;
            int gm = (h * 64 + q * 16 + m) * 2;
            float r64re = rLtab[gm], r64im = rLtab[gm + 1];
            float pre = rStab[gm],  pim = rStab[gm + 1];     // r^1024
            // pass 1: segment end-state
            float ere = 0.f, eim = 0.f;
            #pragma unroll
            for (int i = 0; i < 16; ++i) {
                int c = 16 * s + i;
                float2 v = *(const float2*)(lds + c * 128 + ((8 * m) ^ SWZ(c)));
                float nre = fmaf(r64re, ere, fmaf(-r64im, eim, v.x));
                eim = fmaf(r64re, eim, fmaf(r64im, ere, v.y));
                ere = nre;
            }
            // Kogge-Stone inclusive scan over segments (guard keeps ranges exact)
            #pragma unroll
            for (int d = 1; d < 16; d <<= 1) {
                float orr = __shfl(ere, (lane - d) & 63, 64);
                float oii = __shfl(eim, (lane - d) & 63, 64);
                if (s >= d) {
                    float nre = fmaf(pre, orr, fmaf(-pim, oii, ere));
                    eim = fmaf(pre, oii, fmaf(pim, orr, eim));
                    ere = nre;
                }
                float t2 = pre * pre - pim * pim;            // p <- p^2
                pim = 2.f * pre * pim;
                pre = t2;
            }
            // exclusive: carry-in = inclusive result of segment s-1
            float cire = __shfl(ere, (lane - 1) & 63, 64);
            float ciim = __shfl(eim, (lane - 1) & 63, 64);
            if (s == 0) { cire = 0.f; ciim = 0.f; }
            // pass 2: write bf16 carries to the carry region, advance state
            int mh = m >> 2, ml = m & 3;
            #pragma unroll
            for (int i = 0; i < 16; ++i) {
                int c = 16 * s + i;
                float2 v = *(const float2*)(lds + c * 128 + ((8 * m) ^ SWZ(c)));
                int p16 = mh ^ (c & 3) ^ ((c >> 4) & 3);
                *(unsigned int*)(carr + c * 64 + 16 * p16 + 4 * ml) =
                    (unsigned)f2b(cire) | ((unsigned)f2b(ciim) << 16);
                float nre = fmaf(r64re, cire, fmaf(-r64im, ciim, v.x));
                ciim = fmaf(r64re, ciim, fmaf(r64im, cire, v.y));
                cire = nre;
            }
        }
        __syncthreads();
        {   // GEMM3: Y[c][j] += carry[c][n2q] * Pm[32q+n2q][j]
            const short* pmhb = Pmh + (size_t)h * 8192 + q * 32;
            const short* pmlb = Pml + (size_t)h * 8192 + q * 32;
            s16x8 af[4];
            #pragma unroll
            for (int ct = 0; ct < 4; ++ct) {
                int c = w * 64 + ct * 16 + lo;
                int p16 = hi ^ (c & 3) ^ ((c >> 4) & 3);
                af[ct] = *(const s16x8*)(carr + c * 64 + 16 * p16);
            }
            #pragma unroll
            for (int jt = 0; jt < 4; ++jt) {
                s16x8 pfh = *(const s16x8*)(pmhb + (jt * 16 + lo) * 128 + hi * 8);
                s16x8 pfl = *(const s16x8*)(pmlb + (jt * 16 + lo) * 128 + hi * 8);
                #pragma unroll
                for (int ct = 0; ct < 4; ++ct) {
                    acc[ct][jt] = __builtin_amdgcn_mfma_f32_16x16x32_bf16(af[ct], pfh, acc[ct][jt], 0, 0, 0);
                    acc[ct][jt] = __builtin_amdgcn_mfma_f32_16x16x32_bf16(af[ct], pfl, acc[ct][jt], 0, 0, 0);
                }
            }
        }
        if (q < 3) gemm1(q + 1);    // same phase: S last read by scan(q), done
    }

    // ---- Y staging: acc -> bf16 [c=256][j=64] (128B rows), single rounding
    #pragma unroll
    for (int ct = 0; ct < 4; ++ct) {
        #pragma unroll
        for (int jt = 0; jt < 4; ++jt) {
            int j = jt * 16 + lo;
            #pragma unroll
            for (int rg = 0; rg < 4; ++rg) {
                int c = w * 64 + ct * 16 + hi * 4 + rg;
                *(unsigned short*)(lds + c * 128 + ((2 * j) ^ SWZ(c))) = f2b(acc[ct][jt][rg]);
            }
        }
    }
    __syncthreads();

    // ---- epilogue: mask, coalesced y store, f32 stats -> f64 atomics
    float s1 = 0.f, s2 = 0.f;
    short* yg = (short*)y + (size_t)bh * 16384;
    #pragma unroll
    for (int k = 0; k < 8; ++k) {
        int eidx = (k * 256 + tid) * 8;
        int row = eidx >> 6;
        int byt = ((eidx & 63) * 2) ^ SWZ(row);
        s16x8 yv = *(const s16x8*)(lds + row * 128 + byt);
        s16x8 o;
        #pragma unroll
        for (int e = 0; e < 8; ++e) {
            float vv = b2f((unsigned short)yv[e]);
            vv = (eidx + e < len) ? vv : 0.f;
            o[e] = (short)f2b(vv);
            s1 += vv;
            s2 = fmaf(vv, vv, s2);
        }
        *(s16x8*)(yg + eidx) = o;
    }
    #pragma unroll
    for (int off = 32; off > 0; off >>= 1) {
        s1 += __shfl_down(s1, off, 64);
        s2 += __shfl_down(s2, off, 64);
    }
    if (lane == 0) {
        atomicAdd(&stats[2 * h],     (double)s1);
        atomicAdd(&stats[2 * h + 1], (double)s2);
    }
}

// ---------------- K4: layernorm + FiLM + tanh + residual (8 elems/thread) --
__global__ __launch_bounds__(256) void k4_final(const float* __restrict__ u,
        const bf16* __restrict__ y, const float* __restrict__ cond,
        const float* __restrict__ fw, const float* __restrict__ fb,
        const double* __restrict__ stats, float* __restrict__ out)
{
    int tid = threadIdx.x;
    size_t idx8 = ((size_t)blockIdx.x * 256 + tid) * 8;
    int bh = (int)(idx8 >> 14);
    int b = bh >> 6, h = bh & 63;
    __shared__ float gg[2];
    if (tid == 0) {
        float g = fb[h], bb = fb[64 + h];
        #pragma unroll
        for (int k = 0; k < 3; ++k) {
            g  = fmaf(cond[b * 3 + k], fw[h * 3 + k], g);
            bb = fmaf(cond[b * 3 + k], fw[(64 + h) * 3 + k], bb);
        }
        gg[0] = g; gg[1] = bb;
    }
    __syncthreads();
    double inv = 1.0 / (16.0 * 16384.0);
    double mean_d = stats[2 * h] * inv;
    double var_d  = stats[2 * h + 1] * inv - mean_d * mean_d;
    float mean = (float)mean_d;
    float rstd = rsqrtf((float)var_d + 1e-5f);
    float gv = gg[0], bv = gg[1];
    float4 u0 = *(const float4*)(u + idx8);
    float4 u1 = *(const float4*)(u + idx8 + 4);
    s16x8 yv = *(const s16x8*)((const short*)y + idx8);
    float uv[8] = {u0.x, u0.y, u0.z, u0.w, u1.x, u1.y, u1.z, u1.w};
    float ov[8];
    #pragma unroll
    for (int e = 0; e < 8; ++e) {
        float z = fmaf((b2f((unsigned short)yv[e]) - mean) * rstd, gv, bv);
        ov[e] = uv[e] + tanhf(z);
    }
    *(float4*)(out + idx8)     = float4{ov[0], ov[1], ov[2], ov[3]};
    *(float4*)(out + idx8 + 4) = float4{ov[4], ov[5], ov[6], ov[7]};
}

// ---------------------------------------------------------------------------
extern "C" void kernel_launch(void* const* d_in, const int* in_sizes, int n_in,
                              void* d_out, int out_size, void* d_ws, size_t ws_size,
                              hipStream_t stream)
{
    const float* u           = (const float*)d_in[0];
    const float* cond        = (const float*)d_in[1];
    const int*   length      = (const int*)  d_in[2];
    const float* log_dt      = (const float*)d_in[3];
    const float* C_ri        = (const float*)d_in[4];
    const float* log_A_real  = (const float*)d_in[5];
    const float* A_imag      = (const float*)d_in[6];
    const float* D           = (const float*)d_in[7];
    const float* film_w      = (const float*)d_in[8];
    const float* film_b      = (const float*)d_in[9];
    float* out = (float*)d_out;

    char* w = (char*)d_ws;
    bf16*   y      = (bf16*)w;                    // 33,554,432 B
    short*  Qh     = (short*)(w + 33554432);      //  1,048,576 B
    short*  Pmh    = (short*)(w + 34603008);      //  1,048,576 B
    short*  Pml    = (short*)(w + 35651584);      //  1,048,576 B
    short*  Klh    = (short*)(w + 36700160);      //    524,288 B
    short*  Kll    = (short*)(w + 37224448);      //    524,288 B
    float*  rLtab  = (float*)(w + 37748736);      //     32,768 B
    float*  rStab  = (float*)(w + 37781504);      //     32,768 B
    double* stats  = (double*)(w + 37814272);     //      1,024 B   (~37.8 MB)

    hipMemsetAsync(stats, 0, 1024, stream);
    hipLaunchKernelGGL(k0_setup, dim3(64),   dim3(256), 0, stream,
                       log_dt, C_ri, log_A_real, A_imag, D,
                       rLtab, rStab, Qh, Pmh, Pml, Klh, Kll);
    hipLaunchKernelGGL(k_fused,  dim3(1024), dim3(256), 0, stream,
                       u, length, rLtab, rStab, Qh, Pmh, Pml, Klh, Kll, y, stats);
    hipLaunchKernelGGL(k4_final, dim3(8192), dim3(256), 0, stream,
                       u, y, cond, film_w, film_b, stats, out);
}